// Round 1
// baseline (10309.125 us; speedup 1.0000x reference)
//
#include <hip/hip_runtime.h>
#include <hip/hip_bf16.h>
#include <stdint.h>

// Acoustic stress-velocity FD propagator, MI355X baseline.
// 2 shots x 512x512, 1000 steps. Fields live in d_ws as zero-border-padded
// f32 arrays (pad=2) so stencils need no branches and match jnp.pad(...,0).

#define NXd 512
#define NZd 512
#define NTd 1000
#define Sd  2
#define Rd  512
#define PXd 516                 // 512 + 2*2 halo
#define PZd 516
#define C1f 1.125f
#define C2f (-1.0f/24.0f)
#define CVXf 1e-4f              // DT/DX  (= DT/DZ, DX==DZ==10)
#define SRC_AMPf 1e-5f          // DT/(DX*DZ)

#define FSZ (Sd*PZd*PXd)        // floats per field (both shots) = 532512
#define P_OFF   0
#define VX_OFF  (FSZ)
#define VZ_OFF  (2*FSZ)
#define CV_OFF  (3*FSZ)                       // DT/DX * 1/rho      (512*512)
#define CP_OFF  (3*FSZ + NZd*NXd)             // DT/DX * rho*vp^2   (512*512)
#define DMP_OFF (3*FSZ + 2*NZd*NXd)           // damp as f32        (512*512)
#define FLAG_OFF (3*FSZ + 3*NZd*NXd)          // 1 int: inputs-are-bf16 flag
#define WS_NEED_BYTES ((size_t)(FLAG_OFF + 1) * 4)

// ---- dtype detection: vp in [1500,4000) -> f32 exponent byte 0x44/0x45.
// If buffer is bf16-packed, bits[15:8] of each u32 are the LOW element's
// exponent byte (0x44/0x45 for all). If genuine f32, those are random
// mantissa bits (~2/256 hit rate). 64 samples separate the cases cleanly.
__global__ void detect_k(const uint32_t* __restrict__ vp_raw, int* __restrict__ flag) {
    int lane = threadIdx.x;
    uint32_t u = vp_raw[lane];
    int hb = (u >> 8) & 0xFF;
    int is_exp = (hb == 0x44 || hb == 0x45) ? 1 : 0;
    unsigned long long m = __ballot(is_exp);
    if (lane == 0) *flag = (__popcll(m) >= 48) ? 1 : 0;
}

__device__ __forceinline__ float load_in(const void* p, int i, int bf) {
    return bf ? __bfloat162float(((const __hip_bfloat16*)p)[i])
              : ((const float*)p)[i];
}

__global__ __launch_bounds__(256) void prep_k(const void* __restrict__ vp,
                                              const void* __restrict__ rho,
                                              const void* __restrict__ damp,
                                              float* __restrict__ ws) {
    int i = blockIdx.x * 256 + threadIdx.x;        // 0 .. 262143
    int bf = *(const int*)(ws + FLAG_OFF);
    float v = load_in(vp, i, bf);
    float r = load_in(rho, i, bf);
    float d = load_in(damp, i, bf);
    ws[CV_OFF + i] = CVXf / r;
    ws[CP_OFF + i] = CVXf * r * v * v;
    ws[DMP_OFF + i] = d;
}

// velocity update over the full grid; extra 4 blocks record receivers of the
// PREVIOUS step (p is read-only here, so no race).
__global__ __launch_bounds__(256) void vstep_k(float* __restrict__ ws,
                                               const int* __restrict__ rcv_x,
                                               const int* __restrict__ rcv_z,
                                               void* __restrict__ out, int t) {
    int b = blockIdx.x;
    if (b < 2048) {
        int gid = b * 256 + threadIdx.x;
        int s = gid >> 18, rem = gid & 262143;
        int z = rem >> 9, x = rem & 511;
        const float* p  = ws + P_OFF;
        float* vx = ws + VX_OFF;
        float* vz = ws + VZ_OFF;
        int base = (s * PZd + z + 2) * PXd + x + 2;
        int ci = z * NXd + x;
        float pc  = p[base];
        float dfx = C1f * (p[base + 1]   - pc) + C2f * (p[base + 2]     - p[base - 1]);
        float dfz = C1f * (p[base + PXd] - pc) + C2f * (p[base + 2*PXd] - p[base - PXd]);
        float cv = ws[CV_OFF + ci], d = ws[DMP_OFF + ci];
        vx[base] = d * (vx[base] + cv * dfx);
        vz[base] = d * (vz[base] + cv * dfz);
    } else if (t > 0) {
        int ridx = (b - 2048) * 256 + threadIdx.x;   // 0..1023
        if (ridx < Sd * Rd) {
            int s = ridx >> 9, r = ridx & 511;
            float val = ws[P_OFF + (s * PZd + rcv_z[r] + 2) * PXd + rcv_x[r] + 2];
            int bf = *(const int*)(ws + FLAG_OFF);
            int oi = (s * NTd + (t - 1)) * Rd + r;
            if (bf) ((__hip_bfloat16*)out)[oi] = __float2bfloat16(val);
            else    ((float*)out)[oi] = val;
        }
    }
}

__global__ __launch_bounds__(256) void pstep_k(float* __restrict__ ws,
                                               const int* __restrict__ src_x,
                                               const int* __restrict__ src_z,
                                               const void* __restrict__ wav, int t) {
    int gid = blockIdx.x * 256 + threadIdx.x;
    int s = gid >> 18, rem = gid & 262143;
    int z = rem >> 9, x = rem & 511;
    float* p = ws + P_OFF;
    const float* vx = ws + VX_OFF;
    const float* vz = ws + VZ_OFF;
    int base = (s * PZd + z + 2) * PXd + x + 2;
    int ci = z * NXd + x;
    float dbx = C1f * (vx[base] - vx[base - 1])   + C2f * (vx[base + 1]   - vx[base - 2]);
    float dbz = C1f * (vz[base] - vz[base - PXd]) + C2f * (vz[base + PXd] - vz[base - 2*PXd]);
    float cp = ws[CP_OFF + ci], d = ws[DMP_OFF + ci];
    float pn = d * (p[base] + cp * (dbx + dbz));
    if (z == src_z[s] && x == src_x[s]) {
        int bf = *(const int*)(ws + FLAG_OFF);
        float w = load_in(wav, s * NTd + t, bf);
        pn += w * SRC_AMPf;
    }
    p[base] = pn;
}

__global__ __launch_bounds__(256) void rec_final_k(const float* __restrict__ ws,
                                                   const int* __restrict__ rcv_x,
                                                   const int* __restrict__ rcv_z,
                                                   void* __restrict__ out) {
    int ridx = blockIdx.x * 256 + threadIdx.x;   // 0..1023
    if (ridx < Sd * Rd) {
        int s = ridx >> 9, r = ridx & 511;
        float val = ws[P_OFF + (s * PZd + rcv_z[r] + 2) * PXd + rcv_x[r] + 2];
        int bf = *(const int*)(ws + FLAG_OFF);
        int oi = (s * NTd + (NTd - 1)) * Rd + r;
        if (bf) ((__hip_bfloat16*)out)[oi] = __float2bfloat16(val);
        else    ((float*)out)[oi] = val;
    }
}

extern "C" void kernel_launch(void* const* d_in, const int* in_sizes, int n_in,
                              void* d_out, int out_size, void* d_ws, size_t ws_size,
                              hipStream_t stream) {
    if (ws_size < WS_NEED_BYTES) return;   // fail loud (wrong answer), not OOB
    float* ws = (float*)d_ws;
    const void* vp   = d_in[0];
    const void* rho  = d_in[1];
    const void* damp = d_in[2];
    const void* wav  = d_in[3];
    const int* src_x = (const int*)d_in[4];
    const int* src_z = (const int*)d_in[5];
    const int* rcv_x = (const int*)d_in[6];
    const int* rcv_z = (const int*)d_in[7];

    // zero p, vx, vz (incl. halo borders) every call — deterministic state
    hipMemsetAsync(ws, 0, (size_t)(3 * FSZ) * 4, stream);
    detect_k<<<1, 64, 0, stream>>>((const uint32_t*)vp, (int*)(ws + FLAG_OFF));
    prep_k<<<1024, 256, 0, stream>>>(vp, rho, damp, ws);

    for (int t = 0; t < NTd; ++t) {
        vstep_k<<<2052, 256, 0, stream>>>(ws, rcv_x, rcv_z, d_out, t);
        pstep_k<<<2048, 256, 0, stream>>>(ws, src_x, src_z, wav, t);
    }
    rec_final_k<<<4, 256, 0, stream>>>(ws, rcv_x, rcv_z, d_out);
}

// Round 2
// 4029.830 us; speedup vs baseline: 2.5582x; 2.5582x over previous
//
#include <hip/hip_runtime.h>
#include <hip/hip_bf16.h>
#include <stdint.h>

// Time-skewed windowed acoustic FD: k=5 steps per launch, 200 launches.
// 256 WGs = 2 shots x (16x8) tiles of 32(z)x64(x); extended region 80x112
// (halo 24 = 4k+4) lives in LDS; state+coeffs in registers across steps.

#define NXd 512
#define NZd 512
#define NTd 1000
#define Sd  2
#define Rd  512
#define C1f 1.125f
#define C2f (-1.0f/24.0f)
#define CVXf 1e-4f              // DT/DX
#define SRC_AMPf 1e-5f          // DT/(DX*DZ)

#define TZ 32
#define TX 64
#define KSTEPS 5
#define Hh 24                   // halo = 4k+4, multiple of 4 (alignment)
#define RLZ 80                  // TZ + 2H
#define RLX 112                 // TX + 2H
#define GPR 28                  // RLX/4 float4 groups per row
#define ACT 448                 // 448 threads x 5 groups = 2240 = RLZ*GPR
#define NI 5

#define FSZ (Sd*NZd*NXd)        // 524288 floats per state field
#define P_OFF   0
#define VX_OFF  FSZ
#define VZ_OFF  (2*FSZ)
#define A_OFF   (3*FSZ)                    // damp
#define B_OFF   (3*FSZ + NZd*NXd)          // damp * DT/DX / rho
#define Q_OFF   (3*FSZ + 2*NZd*NXd)        // damp * DT/DX * rho*vp^2
#define FLAG_OFF (3*FSZ + 3*NZd*NXd)
#define WS_NEED_BYTES ((size_t)(FLAG_OFF + 1) * 4)

__device__ __forceinline__ float4 ld4(const float* p) { return *(const float4*)p; }
__device__ __forceinline__ void st4(float* p, float4 v) { *(float4*)p = v; }

// dtype detection (same mechanism that passed in round 1)
__global__ void detect_k(const uint32_t* __restrict__ vp_raw, int* __restrict__ flag) {
    int lane = threadIdx.x;
    uint32_t u = vp_raw[lane];
    int hb = (u >> 8) & 0xFF;
    int is_exp = (hb == 0x44 || hb == 0x45) ? 1 : 0;
    unsigned long long m = __ballot(is_exp);
    if (lane == 0) *flag = (__popcll(m) >= 48) ? 1 : 0;
}

__device__ __forceinline__ float load_in(const void* p, int i, int bf) {
    return bf ? __bfloat162float(((const __hip_bfloat16*)p)[i])
              : ((const float*)p)[i];
}

__global__ __launch_bounds__(256) void prep_k(const void* __restrict__ vp,
                                              const void* __restrict__ rho,
                                              const void* __restrict__ damp,
                                              float* __restrict__ ws) {
    int i = blockIdx.x * 256 + threadIdx.x;        // 0 .. 262143
    int bf = *(const int*)(ws + FLAG_OFF);
    float v = load_in(vp, i, bf);
    float r = load_in(rho, i, bf);
    float d = load_in(damp, i, bf);
    ws[A_OFF + i] = d;
    ws[B_OFF + i] = d * (CVXf / r);
    ws[Q_OFF + i] = d * (CVXf * r * v * v);
}

__global__ __launch_bounds__(512, 2) void win_k(float* __restrict__ ws,
        void* __restrict__ out, const void* __restrict__ wav,
        const int* __restrict__ sxp, const int* __restrict__ szp,
        const int* __restrict__ rxp, const int* __restrict__ rzp, int t0) {
    __shared__ float lp [RLZ*RLX];
    __shared__ float lvx[RLZ*RLX];
    __shared__ float lvz[RLZ*RLX];

    const int tid = threadIdx.x;
    const int wg  = blockIdx.x;
    const int s   = wg >> 7;
    const int rem = wg & 127;
    const int tz0 = (rem >> 3) * TZ;
    const int tx0 = (rem & 7) * TX;
    const int bf  = *(const int*)(ws + FLAG_OFF);

    float* gp  = ws + P_OFF  + s * (NZd*NXd);
    float* gvx = ws + VX_OFF + s * (NZd*NXd);
    float* gvz = ws + VZ_OFF + s * (NZd*NXd);
    const float* gA = ws + A_OFF;
    const float* gB = ws + B_OFF;
    const float* gQ = ws + Q_OFF;

    // receiver ownership (thread tid handles receiver index tid)
    const int rxv = rxp[tid], rzv = rzp[tid];
    const bool own = (rzv >= tz0 && rzv < tz0 + TZ && rxv >= tx0 && rxv < tx0 + TX);
    const int lrcv = (rzv - tz0 + Hh) * RLX + (rxv - tx0 + Hh);
    const int sxv = sxp[s], szv = szp[s];

    float4 Pv[NI], Vx[NI], Vz[NI], Ca[NI], Cb[NI], Cq[NI];
    const bool act = tid < ACT;
    const float4 zero4 = {0.f, 0.f, 0.f, 0.f};

    // ---- window load: state + coeffs (zero outside domain)
    #pragma unroll
    for (int i = 0; i < NI; ++i) {
        if (act) {
            unsigned g = tid + i * ACT;
            int z = g / GPR;
            int xg4 = (g - z * GPR) * 4;
            int li = z * RLX + xg4;
            int gz = tz0 - Hh + z;
            int gx = tx0 - Hh + xg4;
            bool in = (gz >= 0) && (gz < NZd) && (gx >= 0) && (gx < NXd);
            if (in) {
                int gi = gz * NXd + gx;
                Pv[i] = ld4(gp + gi); Vx[i] = ld4(gvx + gi); Vz[i] = ld4(gvz + gi);
                Ca[i] = ld4(gA + gi); Cb[i] = ld4(gB + gi);  Cq[i] = ld4(gQ + gi);
            } else {
                Pv[i] = zero4; Vx[i] = zero4; Vz[i] = zero4;
                Ca[i] = zero4; Cb[i] = zero4; Cq[i] = zero4;
            }
            st4(lp + li, Pv[i]); st4(lvx + li, Vx[i]); st4(lvz + li, Vz[i]);
        }
    }
    __syncthreads();

    for (int j = 0; j < KSTEPS; ++j) {
        const int t = t0 + j;
        const float wv = (bf ? __bfloat162float(((const __hip_bfloat16*)wav)[s*NTd + t])
                             : ((const float*)wav)[s*NTd + t]) * SRC_AMPf;

        // ---------- V phase: vx,vz <- A*v + B*df(p)
        if (act) {
            #pragma unroll
            for (int i = 0; i < NI; ++i) {
                unsigned g = tid + i * ACT;
                int z = g / GPR;
                int xg4 = (g - z * GPR) * 4;
                int li = z * RLX + xg4;
                int ixm  = li - (xg4 > 0 ? 4 : 0);
                int ixp  = li + (xg4 < (RLX - 4) ? 4 : 0);
                int izm1 = li - (z > 0 ? RLX : 0);
                int izp1 = li + (z < RLZ - 1 ? RLX : 0);
                int izp2 = li + (z < RLZ - 2 ? 2*RLX : (z < RLZ - 1 ? RLX : 0));
                float4 pm  = ld4(lp + ixm);
                float4 pp  = ld4(lp + ixp);
                float4 pzm = ld4(lp + izm1);
                float4 pz1 = ld4(lp + izp1);
                float4 pz2 = ld4(lp + izp2);
                float4 c = Pv[i];
                float4 dfx, dfz;
                dfx.x = C1f*(c.y - c.x) + C2f*(c.z  - pm.w);
                dfx.y = C1f*(c.z - c.y) + C2f*(c.w  - c.x);
                dfx.z = C1f*(c.w - c.z) + C2f*(pp.x - c.y);
                dfx.w = C1f*(pp.x - c.w) + C2f*(pp.y - c.z);
                dfz.x = C1f*(pz1.x - c.x) + C2f*(pz2.x - pzm.x);
                dfz.y = C1f*(pz1.y - c.y) + C2f*(pz2.y - pzm.y);
                dfz.z = C1f*(pz1.z - c.z) + C2f*(pz2.z - pzm.z);
                dfz.w = C1f*(pz1.w - c.w) + C2f*(pz2.w - pzm.w);
                Vx[i].x = Ca[i].x*Vx[i].x + Cb[i].x*dfx.x;
                Vx[i].y = Ca[i].y*Vx[i].y + Cb[i].y*dfx.y;
                Vx[i].z = Ca[i].z*Vx[i].z + Cb[i].z*dfx.z;
                Vx[i].w = Ca[i].w*Vx[i].w + Cb[i].w*dfx.w;
                Vz[i].x = Ca[i].x*Vz[i].x + Cb[i].x*dfz.x;
                Vz[i].y = Ca[i].y*Vz[i].y + Cb[i].y*dfz.y;
                Vz[i].z = Ca[i].z*Vz[i].z + Cb[i].z*dfz.z;
                Vz[i].w = Ca[i].w*Vz[i].w + Cb[i].w*dfz.w;
                st4(lvx + li, Vx[i]);
                st4(lvz + li, Vz[i]);
            }
        }
        __syncthreads();

        // ---------- P phase: p <- A*p + Q*(dbx(vx)+dbz(vz)) [+ source]
        if (act) {
            #pragma unroll
            for (int i = 0; i < NI; ++i) {
                unsigned g = tid + i * ACT;
                int z = g / GPR;
                int xg4 = (g - z * GPR) * 4;
                int li = z * RLX + xg4;
                int ixm  = li - (xg4 > 0 ? 4 : 0);
                int ixp  = li + (xg4 < (RLX - 4) ? 4 : 0);
                int izm1 = li - (z > 0 ? RLX : 0);
                int izm2 = li - (z > 1 ? 2*RLX : (z > 0 ? RLX : 0));
                int izp1 = li + (z < RLZ - 1 ? RLX : 0);
                float4 vm  = ld4(lvx + ixm);
                float4 vxp = ld4(lvx + ixp);
                float4 wm2 = ld4(lvz + izm2);
                float4 wm1 = ld4(lvz + izm1);
                float4 w1  = ld4(lvz + izp1);
                float4 cx = Vx[i], cz = Vz[i], pc = Pv[i];
                float4 dbx, dbz;
                dbx.x = C1f*(cx.x - vm.w) + C2f*(cx.y  - vm.z);
                dbx.y = C1f*(cx.y - cx.x) + C2f*(cx.z  - vm.w);
                dbx.z = C1f*(cx.z - cx.y) + C2f*(cx.w  - cx.x);
                dbx.w = C1f*(cx.w - cx.z) + C2f*(vxp.x - cx.y);
                dbz.x = C1f*(cz.x - wm1.x) + C2f*(w1.x - wm2.x);
                dbz.y = C1f*(cz.y - wm1.y) + C2f*(w1.y - wm2.y);
                dbz.z = C1f*(cz.z - wm1.z) + C2f*(w1.z - wm2.z);
                dbz.w = C1f*(cz.w - wm1.w) + C2f*(w1.w - wm2.w);
                Pv[i].x = Ca[i].x*pc.x + Cq[i].x*(dbx.x + dbz.x);
                Pv[i].y = Ca[i].y*pc.y + Cq[i].y*(dbx.y + dbz.y);
                Pv[i].z = Ca[i].z*pc.z + Cq[i].z*(dbx.z + dbz.z);
                Pv[i].w = Ca[i].w*pc.w + Cq[i].w*(dbx.w + dbz.w);
                // source injection (global-coordinate check -> halos get it too)
                int gz = tz0 - Hh + z;
                if (gz == szv) {
                    int dcol = sxv - (tx0 - Hh + xg4);
                    if      (dcol == 0) Pv[i].x += wv;
                    else if (dcol == 1) Pv[i].y += wv;
                    else if (dcol == 2) Pv[i].z += wv;
                    else if (dcol == 3) Pv[i].w += wv;
                }
                st4(lp + li, Pv[i]);
            }
        }
        __syncthreads();

        // ---------- receivers (unique owner tile per (rz,rx))
        if (own) {
            float val = lp[lrcv];
            int oi = (s * NTd + t) * Rd + tid;
            if (bf) ((__hip_bfloat16*)out)[oi] = __float2bfloat16(val);
            else    ((float*)out)[oi] = val;
        }
    }

    // ---- window store: tile interior only (registers are current state)
    if (act) {
        #pragma unroll
        for (int i = 0; i < NI; ++i) {
            unsigned g = tid + i * ACT;
            int z = g / GPR;
            int xg4 = (g - z * GPR) * 4;
            int gz = tz0 - Hh + z;
            int gx = tx0 - Hh + xg4;
            if (gz >= tz0 && gz < tz0 + TZ && gx >= tx0 && gx < tx0 + TX) {
                int gi = gz * NXd + gx;
                st4(gp + gi, Pv[i]);
                st4(gvx + gi, Vx[i]);
                st4(gvz + gi, Vz[i]);
            }
        }
    }
}

extern "C" void kernel_launch(void* const* d_in, const int* in_sizes, int n_in,
                              void* d_out, int out_size, void* d_ws, size_t ws_size,
                              hipStream_t stream) {
    if (ws_size < WS_NEED_BYTES) return;
    float* ws = (float*)d_ws;
    const void* vp   = d_in[0];
    const void* rho  = d_in[1];
    const void* damp = d_in[2];
    const void* wav  = d_in[3];
    const int* src_x = (const int*)d_in[4];
    const int* src_z = (const int*)d_in[5];
    const int* rcv_x = (const int*)d_in[6];
    const int* rcv_z = (const int*)d_in[7];

    hipMemsetAsync(ws, 0, (size_t)(3 * FSZ) * 4, stream);   // zero state
    detect_k<<<1, 64, 0, stream>>>((const uint32_t*)vp, (int*)(ws + FLAG_OFF));
    prep_k<<<1024, 256, 0, stream>>>(vp, rho, damp, ws);

    for (int w = 0; w < NTd / KSTEPS; ++w) {
        win_k<<<256, 512, 0, stream>>>(ws, d_out, wav, src_x, src_z,
                                       rcv_x, rcv_z, w * KSTEPS);
    }
}

// Round 3
// 3467.987 us; speedup vs baseline: 2.9727x; 1.1620x over previous
//
#include <hip/hip_runtime.h>
#include <hip/hip_bf16.h>
#include <stdint.h>

// Time-skewed windowed acoustic FD, k=5 steps/launch, 200 launches.
// Register z-blocking: thread owns 5 consecutive z-rows x 4 x-values.
// x-neighbor exchange via __shfl, z-exchange via LDS (p: all rows,
// vz: 3 boundary rows). vx needs no LDS at all.

#define NXd 512
#define NZd 512
#define NTd 1000
#define Sd  2
#define Rd  512
#define C1f 1.125f
#define C2f (-1.0f/24.0f)
#define CVXf 1e-4f              // DT/DX
#define SRC_AMPf 1e-5f          // DT/(DX*DZ)

#define TZ 32
#define TX 64
#define KSTEPS 5
#define Hz 24                   // z-halo >= 4k+4
#define Hx 32                   // x-halo (widened so 32 lanes cover RLX)
#define RLZ 80                  // TZ + 2*Hz
#define RLX 128                 // TX + 2*Hx
#define ZB 5                    // z-rows per thread
#define NZB 16                  // z-blocks (NZB*ZB == RLZ)

#define FSZ (Sd*NZd*NXd)
#define P_OFF   0
#define VX_OFF  FSZ
#define VZ_OFF  (2*FSZ)
#define A_OFF   (3*FSZ)
#define B_OFF   (3*FSZ + NZd*NXd)
#define Q_OFF   (3*FSZ + 2*NZd*NXd)
#define FLAG_OFF (3*FSZ + 3*NZd*NXd)
#define WS_NEED_BYTES ((size_t)(FLAG_OFF + 1) * 4)

__device__ __forceinline__ float4 ld4(const float* p) { return *(const float4*)p; }
__device__ __forceinline__ void st4(float* p, float4 v) { *(float4*)p = v; }

__global__ void detect_k(const uint32_t* __restrict__ vp_raw, int* __restrict__ flag) {
    int lane = threadIdx.x;
    uint32_t u = vp_raw[lane];
    int hb = (u >> 8) & 0xFF;
    int is_exp = (hb == 0x44 || hb == 0x45) ? 1 : 0;
    unsigned long long m = __ballot(is_exp);
    if (lane == 0) *flag = (__popcll(m) >= 48) ? 1 : 0;
}

__device__ __forceinline__ float load_in(const void* p, int i, int bf) {
    return bf ? __bfloat162float(((const __hip_bfloat16*)p)[i])
              : ((const float*)p)[i];
}

__global__ __launch_bounds__(256) void prep_k(const void* __restrict__ vp,
                                              const void* __restrict__ rho,
                                              const void* __restrict__ damp,
                                              float* __restrict__ ws) {
    int i = blockIdx.x * 256 + threadIdx.x;
    int bf = *(const int*)(ws + FLAG_OFF);
    float v = load_in(vp, i, bf);
    float r = load_in(rho, i, bf);
    float d = load_in(damp, i, bf);
    ws[A_OFF + i] = d;
    ws[B_OFF + i] = d * (CVXf / r);
    ws[Q_OFF + i] = d * (CVXf * r * v * v);
}

__global__ __launch_bounds__(512, 2) void win_k(float* __restrict__ ws,
        void* __restrict__ out, const void* __restrict__ wav,
        const int* __restrict__ sxp, const int* __restrict__ szp,
        const int* __restrict__ rxp, const int* __restrict__ rzp, int t0) {
    __shared__ float lp [RLZ*RLX];
    __shared__ float lvz[RLZ*RLX];

    const int tid  = threadIdx.x;
    const int lane = tid & 63;
    const int xg   = tid & 31;          // x-group (4 floats)
    const int zblk = tid >> 5;          // 0..15
    const int zb0  = zblk * ZB;
    const int xo   = xg * 4;

    const int wg  = blockIdx.x;
    const int s   = wg >> 7;
    const int rem = wg & 127;
    const int tz0 = (rem >> 3) * TZ;
    const int tx0 = (rem & 7) * TX;
    const int bf  = *(const int*)(ws + FLAG_OFF);

    float* gp  = ws + P_OFF  + s * (NZd*NXd);
    float* gvx = ws + VX_OFF + s * (NZd*NXd);
    float* gvz = ws + VZ_OFF + s * (NZd*NXd);
    const float* gA = ws + A_OFF;
    const float* gB = ws + B_OFF;
    const float* gQ = ws + Q_OFF;

    // receiver ownership (thread tid handles receiver tid)
    const int rxv = rxp[tid], rzv = rzp[tid];
    const bool own = (rzv >= tz0 && rzv < tz0 + TZ && rxv >= tx0 && rxv < tx0 + TX);
    const int lrcv = (rzv - tz0 + Hz) * RLX + (rxv - tx0 + Hx);
    const int sxv = sxp[s], szv = szp[s];

    // clamped z-neighbor row indices (region edges tolerate garbage)
    const int zPm  = (zb0 - 1 < 0) ? 0 : zb0 - 1;
    const int zPn0 = (zb0 + ZB     > RLZ - 1) ? RLZ - 1 : zb0 + ZB;
    const int zPn1 = (zb0 + ZB + 1 > RLZ - 1) ? RLZ - 1 : zb0 + ZB + 1;
    const int zVm2 = (zb0 - 2 < 0) ? 0 : zb0 - 2;
    const int zVm1 = zPm;
    const int zVn0 = zPn0;

    float4 Pv[ZB], Vx[ZB], Vz[ZB], Ca[ZB], Cb[ZB], Cq[ZB];
    const float4 zero4 = {0.f, 0.f, 0.f, 0.f};

    // ---- window load
    #pragma unroll
    for (int r = 0; r < ZB; ++r) {
        int z = zb0 + r;
        int gz = tz0 - Hz + z;
        int gx = tx0 - Hx + xo;
        int li = z * RLX + xo;
        bool in = (gz >= 0) && (gz < NZd) && (gx >= 0) && (gx < NXd);
        if (in) {
            int gi = gz * NXd + gx;
            Pv[r] = ld4(gp + gi); Vx[r] = ld4(gvx + gi); Vz[r] = ld4(gvz + gi);
            Ca[r] = ld4(gA + gi); Cb[r] = ld4(gB + gi);  Cq[r] = ld4(gQ + gi);
        } else {
            Pv[r] = zero4; Vx[r] = zero4; Vz[r] = zero4;
            Ca[r] = zero4; Cb[r] = zero4; Cq[r] = zero4;
        }
        st4(lp + li, Pv[r]);
        st4(lvz + li, Vz[r]);
    }
    __syncthreads();

    for (int j = 0; j < KSTEPS; ++j) {
        const int t = t0 + j;
        const float wv = (bf ? __bfloat162float(((const __hip_bfloat16*)wav)[s*NTd + t])
                             : ((const float*)wav)[s*NTd + t]) * SRC_AMPf;

        // ---------- V phase: vx,vz <- A*v + B*df(p)
        {
            float4 pPm  = ld4(lp + zPm  * RLX + xo);
            float4 pNx0 = ld4(lp + zPn0 * RLX + xo);
            float4 pNx1 = ld4(lp + zPn1 * RLX + xo);
            #pragma unroll
            for (int r = 0; r < ZB; ++r) {
                float4 c = Pv[r];
                float pmw = __shfl(c.w, lane - 1);
                float ppx = __shfl(c.x, lane + 1);
                float ppy = __shfl(c.y, lane + 1);
                float4 pzm = (r == 0) ? pPm : Pv[(r == 0) ? 0 : r - 1];
                float4 pz1 = (r == ZB-1) ? pNx0 : Pv[(r == ZB-1) ? ZB-1 : r + 1];
                float4 pz2 = (r == ZB-1) ? pNx1 : ((r == ZB-2) ? pNx0 : Pv[(r >= ZB-2) ? ZB-1 : r + 2]);
                float4 dfx, dfz;
                dfx.x = C1f*(c.y - c.x) + C2f*(c.z - pmw);
                dfx.y = C1f*(c.z - c.y) + C2f*(c.w - c.x);
                dfx.z = C1f*(c.w - c.z) + C2f*(ppx - c.y);
                dfx.w = C1f*(ppx - c.w) + C2f*(ppy - c.z);
                dfz.x = C1f*(pz1.x - c.x) + C2f*(pz2.x - pzm.x);
                dfz.y = C1f*(pz1.y - c.y) + C2f*(pz2.y - pzm.y);
                dfz.z = C1f*(pz1.z - c.z) + C2f*(pz2.z - pzm.z);
                dfz.w = C1f*(pz1.w - c.w) + C2f*(pz2.w - pzm.w);
                Vx[r].x = Ca[r].x*Vx[r].x + Cb[r].x*dfx.x;
                Vx[r].y = Ca[r].y*Vx[r].y + Cb[r].y*dfx.y;
                Vx[r].z = Ca[r].z*Vx[r].z + Cb[r].z*dfx.z;
                Vx[r].w = Ca[r].w*Vx[r].w + Cb[r].w*dfx.w;
                Vz[r].x = Ca[r].x*Vz[r].x + Cb[r].x*dfz.x;
                Vz[r].y = Ca[r].y*Vz[r].y + Cb[r].y*dfz.y;
                Vz[r].z = Ca[r].z*Vz[r].z + Cb[r].z*dfz.z;
                Vz[r].w = Ca[r].w*Vz[r].w + Cb[r].w*dfz.w;
            }
            // publish vz boundary rows (rows 0,3,4 cover all cross-block needs)
            st4(lvz + (zb0 + 0) * RLX + xo, Vz[0]);
            st4(lvz + (zb0 + 3) * RLX + xo, Vz[3]);
            st4(lvz + (zb0 + 4) * RLX + xo, Vz[4]);
        }
        __syncthreads();

        // ---------- P phase: p <- A*p + Q*(dbx(vx)+dbz(vz)) [+ source]
        {
            float4 vm2 = ld4(lvz + zVm2 * RLX + xo);
            float4 vm1 = ld4(lvz + zVm1 * RLX + xo);
            float4 vn0 = ld4(lvz + zVn0 * RLX + xo);
            #pragma unroll
            for (int r = 0; r < ZB; ++r) {
                float4 cx = Vx[r], cz = Vz[r];
                float vmz = __shfl(cx.z, lane - 1);
                float vmw = __shfl(cx.w, lane - 1);
                float vpx = __shfl(cx.x, lane + 1);
                float4 zm2 = (r == 0) ? vm2 : ((r == 1) ? vm1 : Vz[(r >= 2) ? r - 2 : 0]);
                float4 zm1 = (r == 0) ? vm1 : Vz[(r == 0) ? 0 : r - 1];
                float4 zp1 = (r == ZB-1) ? vn0 : Vz[(r == ZB-1) ? ZB-1 : r + 1];
                float4 dbx, dbz;
                dbx.x = C1f*(cx.x - vmw)  + C2f*(cx.y - vmz);
                dbx.y = C1f*(cx.y - cx.x) + C2f*(cx.z - vmw);
                dbx.z = C1f*(cx.z - cx.y) + C2f*(cx.w - cx.x);
                dbx.w = C1f*(cx.w - cx.z) + C2f*(vpx  - cx.y);
                dbz.x = C1f*(cz.x - zm1.x) + C2f*(zp1.x - zm2.x);
                dbz.y = C1f*(cz.y - zm1.y) + C2f*(zp1.y - zm2.y);
                dbz.z = C1f*(cz.z - zm1.z) + C2f*(zp1.z - zm2.z);
                dbz.w = C1f*(cz.w - zm1.w) + C2f*(zp1.w - zm2.w);
                Pv[r].x = Ca[r].x*Pv[r].x + Cq[r].x*(dbx.x + dbz.x);
                Pv[r].y = Ca[r].y*Pv[r].y + Cq[r].y*(dbx.y + dbz.y);
                Pv[r].z = Ca[r].z*Pv[r].z + Cq[r].z*(dbx.z + dbz.z);
                Pv[r].w = Ca[r].w*Pv[r].w + Cq[r].w*(dbx.w + dbz.w);
                int gz = tz0 - Hz + zb0 + r;
                if (gz == szv) {
                    int dcol = sxv - (tx0 - Hx + xo);
                    if      (dcol == 0) Pv[r].x += wv;
                    else if (dcol == 1) Pv[r].y += wv;
                    else if (dcol == 2) Pv[r].z += wv;
                    else if (dcol == 3) Pv[r].w += wv;
                }
                st4(lp + (zb0 + r) * RLX + xo, Pv[r]);   // publish all p rows
            }
        }
        __syncthreads();

        // ---------- receivers (p of step t is in lp; no writer touches lp
        // until next step's P phase, and lvz writes don't alias)
        if (own) {
            float val = lp[lrcv];
            int oi = (s * NTd + t) * Rd + tid;
            if (bf) ((__hip_bfloat16*)out)[oi] = __float2bfloat16(val);
            else    ((float*)out)[oi] = val;
        }
    }

    // ---- window store: tile interior only
    #pragma unroll
    for (int r = 0; r < ZB; ++r) {
        int z = zb0 + r;
        int gz = tz0 - Hz + z;
        int gx = tx0 - Hx + xo;
        if (z >= Hz && z < Hz + TZ && xo >= Hx && xo < Hx + TX) {
            int gi = gz * NXd + gx;
            st4(gp + gi, Pv[r]);
            st4(gvx + gi, Vx[r]);
            st4(gvz + gi, Vz[r]);
        }
    }
}

extern "C" void kernel_launch(void* const* d_in, const int* in_sizes, int n_in,
                              void* d_out, int out_size, void* d_ws, size_t ws_size,
                              hipStream_t stream) {
    if (ws_size < WS_NEED_BYTES) return;
    float* ws = (float*)d_ws;
    const void* vp   = d_in[0];
    const void* rho  = d_in[1];
    const void* damp = d_in[2];
    const void* wav  = d_in[3];
    const int* src_x = (const int*)d_in[4];
    const int* src_z = (const int*)d_in[5];
    const int* rcv_x = (const int*)d_in[6];
    const int* rcv_z = (const int*)d_in[7];

    hipMemsetAsync(ws, 0, (size_t)(3 * FSZ) * 4, stream);
    detect_k<<<1, 64, 0, stream>>>((const uint32_t*)vp, (int*)(ws + FLAG_OFF));
    prep_k<<<1024, 256, 0, stream>>>(vp, rho, damp, ws);

    for (int w = 0; w < NTd / KSTEPS; ++w) {
        win_k<<<256, 512, 0, stream>>>(ws, d_out, wav, src_x, src_z,
                                       rcv_x, rcv_z, w * KSTEPS);
    }
}

// Round 5
// 3435.644 us; speedup vs baseline: 3.0006x; 1.0094x over previous
//
#include <hip/hip_runtime.h>
#include <hip/hip_bf16.h>
#include <stdint.h>

// Time-skewed windowed acoustic FD, k=5 steps/launch, 200 launches.
// Register z-blocking (5 rows x 4 x per thread), DPP wave-shift x-exchange,
// LDS z-exchange (p all rows, vz rows 0/3/4), trapezoid z-skip.
// DPP direction fix vs round 4: wave_shr:1 (0x138) = value from lane-1,
// wave_shl:1 (0x130) = value from lane+1 (rocPRIM scan convention).

#define NXd 512
#define NZd 512
#define NTd 1000
#define Sd  2
#define Rd  512
#define C1f 1.125f
#define C2f (-1.0f/24.0f)
#define CVXf 1e-4f              // DT/DX
#define SRC_AMPf 1e-5f          // DT/(DX*DZ)

#define TZ 32
#define TX 64
#define KSTEPS 5
#define Hz 24                   // z-halo >= 4k+4
#define Hx 32                   // x-halo (32 lanes x 4 floats = 128 wide)
#define RLZ 80                  // TZ + 2*Hz
#define RLX 128                 // TX + 2*Hx
#define ZB 5                    // z-rows per thread

#define FSZ (Sd*NZd*NXd)
#define P_OFF   0
#define VX_OFF  FSZ
#define VZ_OFF  (2*FSZ)
#define A_OFF   (3*FSZ)
#define B_OFF   (3*FSZ + NZd*NXd)
#define Q_OFF   (3*FSZ + 2*NZd*NXd)
#define FLAG_OFF (3*FSZ + 3*NZd*NXd)
#define WS_NEED_BYTES ((size_t)(FLAG_OFF + 1) * 4)

__device__ __forceinline__ float4 ld4(const float* p) { return *(const float4*)p; }
__device__ __forceinline__ void st4(float* p, float4 v) { *(float4*)p = v; }

// DPP wave shifts. wave_shr:1 (0x138): lane n receives lane n-1's value.
// wave_shl:1 (0x130): lane n receives lane n+1's value.
// bound_ctrl=true -> edge lanes read 0 (tolerated: region x-edge halo).
__device__ __forceinline__ float sh_up1(float v) {   // returns lane-1's v
    return __int_as_float(__builtin_amdgcn_update_dpp(
        0, __float_as_int(v), 0x138, 0xF, 0xF, true));
}
__device__ __forceinline__ float sh_dn1(float v) {   // returns lane+1's v
    return __int_as_float(__builtin_amdgcn_update_dpp(
        0, __float_as_int(v), 0x130, 0xF, 0xF, true));
}

__global__ void detect_k(const uint32_t* __restrict__ vp_raw, int* __restrict__ flag) {
    int lane = threadIdx.x;
    uint32_t u = vp_raw[lane];
    int hb = (u >> 8) & 0xFF;
    int is_exp = (hb == 0x44 || hb == 0x45) ? 1 : 0;
    unsigned long long m = __ballot(is_exp);
    if (lane == 0) *flag = (__popcll(m) >= 48) ? 1 : 0;
}

__device__ __forceinline__ float load_in(const void* p, int i, int bf) {
    return bf ? __bfloat162float(((const __hip_bfloat16*)p)[i])
              : ((const float*)p)[i];
}

__global__ __launch_bounds__(256) void prep_k(const void* __restrict__ vp,
                                              const void* __restrict__ rho,
                                              const void* __restrict__ damp,
                                              float* __restrict__ ws) {
    int i = blockIdx.x * 256 + threadIdx.x;
    int bf = *(const int*)(ws + FLAG_OFF);
    float v = load_in(vp, i, bf);
    float r = load_in(rho, i, bf);
    float d = load_in(damp, i, bf);
    ws[A_OFF + i] = d;
    ws[B_OFF + i] = d * (CVXf / r);
    ws[Q_OFF + i] = d * (CVXf * r * v * v);
}

__global__ __launch_bounds__(512, 2) void win_k(float* __restrict__ ws,
        void* __restrict__ out, const void* __restrict__ wav,
        const int* __restrict__ sxp, const int* __restrict__ szp,
        const int* __restrict__ rxp, const int* __restrict__ rzp, int t0) {
    __shared__ float lp [RLZ*RLX];
    __shared__ float lvz[RLZ*RLX];

    const int tid  = threadIdx.x;
    const int xg   = tid & 31;          // x-group (4 floats)
    const int zblk = tid >> 5;          // 0..15
    const int zb0  = zblk * ZB;
    const int xo   = xg * 4;

    const int wg  = blockIdx.x;
    const int s   = wg >> 7;
    const int rem = wg & 127;
    const int tz0 = (rem >> 3) * TZ;
    const int tx0 = (rem & 7) * TX;
    const int bf  = *(const int*)(ws + FLAG_OFF);

    float* gp  = ws + P_OFF  + s * (NZd*NXd);
    float* gvx = ws + VX_OFF + s * (NZd*NXd);
    float* gvz = ws + VZ_OFF + s * (NZd*NXd);
    const float* gA = ws + A_OFF;
    const float* gB = ws + B_OFF;
    const float* gQ = ws + Q_OFF;

    const int rxv = rxp[tid], rzv = rzp[tid];
    const bool own = (rzv >= tz0 && rzv < tz0 + TZ && rxv >= tx0 && rxv < tx0 + TX);
    const int lrcv = (rzv - tz0 + Hz) * RLX + (rxv - tx0 + Hx);
    const int sxv = sxp[s], szv = szp[s];

    // clamped z-neighbor row indices
    const int zPm  = (zb0 - 1 < 0) ? 0 : zb0 - 1;
    const int zPn0 = (zb0 + ZB     > RLZ - 1) ? RLZ - 1 : zb0 + ZB;
    const int zPn1 = (zb0 + ZB + 1 > RLZ - 1) ? RLZ - 1 : zb0 + ZB + 1;
    const int zVm2 = (zb0 - 2 < 0) ? 0 : zb0 - 2;
    const int zVm1 = zPm;
    const int zVn0 = zPn0;

    float4 Pv[ZB], Vx[ZB], Vz[ZB], Ca[ZB], Cb[ZB], Cq[ZB];
    const float4 zero4 = {0.f, 0.f, 0.f, 0.f};

    // ---- window load
    #pragma unroll
    for (int r = 0; r < ZB; ++r) {
        int z = zb0 + r;
        int gz = tz0 - Hz + z;
        int gx = tx0 - Hx + xo;
        int li = z * RLX + xo;
        bool in = (gz >= 0) && (gz < NZd) && (gx >= 0) && (gx < NXd);
        if (in) {
            int gi = gz * NXd + gx;
            Pv[r] = ld4(gp + gi); Vx[r] = ld4(gvx + gi); Vz[r] = ld4(gvz + gi);
            Ca[r] = ld4(gA + gi); Cb[r] = ld4(gB + gi);  Cq[r] = ld4(gQ + gi);
        } else {
            Pv[r] = zero4; Vx[r] = zero4; Vz[r] = zero4;
            Ca[r] = zero4; Cb[r] = zero4; Cq[r] = zero4;
        }
        st4(lp + li, Pv[r]);
        st4(lvz + li, Vz[r]);
    }
    __syncthreads();

    for (int j = 0; j < KSTEPS; ++j) {
        const int t = t0 + j;
        const float wv = (bf ? __bfloat162float(((const __hip_bfloat16*)wav)[s*NTd + t])
                             : ((const float*)wav)[s*NTd + t]) * SRC_AMPf;

        // trapezoid bounds: only cells in tile+/-m influence the output
        const int mV = 4 * (KSTEPS - 1 - j) + 2;
        const int mP = mV - 2;
        const bool actV = (zb0 + ZB > Hz - mV) && (zb0 < Hz + TZ + mV);
        const bool actP = (zb0 + ZB > Hz - mP) && (zb0 < Hz + TZ + mP);

        // ---------- V phase: vx,vz <- A*v + B*df(p)
        if (actV) {
            float4 pPm  = ld4(lp + zPm  * RLX + xo);
            float4 pNx0 = ld4(lp + zPn0 * RLX + xo);
            float4 pNx1 = ld4(lp + zPn1 * RLX + xo);
            #pragma unroll
            for (int r = 0; r < ZB; ++r) {
                float4 c = Pv[r];
                float pmw = sh_up1(c.w);
                float ppx = sh_dn1(c.x);
                float ppy = sh_dn1(c.y);
                float4 pzm = (r == 0) ? pPm : Pv[(r == 0) ? 0 : r - 1];
                float4 pz1 = (r == ZB-1) ? pNx0 : Pv[(r == ZB-1) ? ZB-1 : r + 1];
                float4 pz2 = (r == ZB-1) ? pNx1 : ((r == ZB-2) ? pNx0 : Pv[(r >= ZB-2) ? ZB-1 : r + 2]);
                float4 dfx, dfz;
                dfx.x = C1f*(c.y - c.x) + C2f*(c.z - pmw);
                dfx.y = C1f*(c.z - c.y) + C2f*(c.w - c.x);
                dfx.z = C1f*(c.w - c.z) + C2f*(ppx - c.y);
                dfx.w = C1f*(ppx - c.w) + C2f*(ppy - c.z);
                dfz.x = C1f*(pz1.x - c.x) + C2f*(pz2.x - pzm.x);
                dfz.y = C1f*(pz1.y - c.y) + C2f*(pz2.y - pzm.y);
                dfz.z = C1f*(pz1.z - c.z) + C2f*(pz2.z - pzm.z);
                dfz.w = C1f*(pz1.w - c.w) + C2f*(pz2.w - pzm.w);
                Vx[r].x = Ca[r].x*Vx[r].x + Cb[r].x*dfx.x;
                Vx[r].y = Ca[r].y*Vx[r].y + Cb[r].y*dfx.y;
                Vx[r].z = Ca[r].z*Vx[r].z + Cb[r].z*dfx.z;
                Vx[r].w = Ca[r].w*Vx[r].w + Cb[r].w*dfx.w;
                Vz[r].x = Ca[r].x*Vz[r].x + Cb[r].x*dfz.x;
                Vz[r].y = Ca[r].y*Vz[r].y + Cb[r].y*dfz.y;
                Vz[r].z = Ca[r].z*Vz[r].z + Cb[r].z*dfz.z;
                Vz[r].w = Ca[r].w*Vz[r].w + Cb[r].w*dfz.w;
            }
            // publish vz boundary rows (0,3,4 cover all cross-block needs)
            st4(lvz + (zb0 + 0) * RLX + xo, Vz[0]);
            st4(lvz + (zb0 + 3) * RLX + xo, Vz[3]);
            st4(lvz + (zb0 + 4) * RLX + xo, Vz[4]);
        }
        __syncthreads();

        // ---------- P phase: p <- A*p + Q*(dbx(vx)+dbz(vz)) [+ source]
        if (actP) {
            float4 vm2 = ld4(lvz + zVm2 * RLX + xo);
            float4 vm1 = ld4(lvz + zVm1 * RLX + xo);
            float4 vn0 = ld4(lvz + zVn0 * RLX + xo);
            #pragma unroll
            for (int r = 0; r < ZB; ++r) {
                float4 cx = Vx[r], cz = Vz[r];
                float vmz = sh_up1(cx.z);
                float vmw = sh_up1(cx.w);
                float vpx = sh_dn1(cx.x);
                float4 zm2 = (r == 0) ? vm2 : ((r == 1) ? vm1 : Vz[(r >= 2) ? r - 2 : 0]);
                float4 zm1 = (r == 0) ? vm1 : Vz[(r == 0) ? 0 : r - 1];
                float4 zp1 = (r == ZB-1) ? vn0 : Vz[(r == ZB-1) ? ZB-1 : r + 1];
                float4 dbx, dbz;
                dbx.x = C1f*(cx.x - vmw)  + C2f*(cx.y - vmz);
                dbx.y = C1f*(cx.y - cx.x) + C2f*(cx.z - vmw);
                dbx.z = C1f*(cx.z - cx.y) + C2f*(cx.w - cx.x);
                dbx.w = C1f*(cx.w - cx.z) + C2f*(vpx  - cx.y);
                dbz.x = C1f*(cz.x - zm1.x) + C2f*(zp1.x - zm2.x);
                dbz.y = C1f*(cz.y - zm1.y) + C2f*(zp1.y - zm2.y);
                dbz.z = C1f*(cz.z - zm1.z) + C2f*(zp1.z - zm2.z);
                dbz.w = C1f*(cz.w - zm1.w) + C2f*(zp1.w - zm2.w);
                Pv[r].x = Ca[r].x*Pv[r].x + Cq[r].x*(dbx.x + dbz.x);
                Pv[r].y = Ca[r].y*Pv[r].y + Cq[r].y*(dbx.y + dbz.y);
                Pv[r].z = Ca[r].z*Pv[r].z + Cq[r].z*(dbx.z + dbz.z);
                Pv[r].w = Ca[r].w*Pv[r].w + Cq[r].w*(dbx.w + dbz.w);
                int gz = tz0 - Hz + zb0 + r;
                if (gz == szv) {
                    int dcol = sxv - (tx0 - Hx + xo);
                    if      (dcol == 0) Pv[r].x += wv;
                    else if (dcol == 1) Pv[r].y += wv;
                    else if (dcol == 2) Pv[r].z += wv;
                    else if (dcol == 3) Pv[r].w += wv;
                }
                st4(lp + (zb0 + r) * RLX + xo, Pv[r]);
            }
        }
        __syncthreads();

        // ---------- receivers (read after P barrier; next lp write is after
        // the NEXT V barrier, so no race)
        if (own) {
            float val = lp[lrcv];
            int oi = (s * NTd + t) * Rd + tid;
            if (bf) ((__hip_bfloat16*)out)[oi] = __float2bfloat16(val);
            else    ((float*)out)[oi] = val;
        }
    }

    // ---- window store: tile interior only
    #pragma unroll
    for (int r = 0; r < ZB; ++r) {
        int z = zb0 + r;
        int gz = tz0 - Hz + z;
        int gx = tx0 - Hx + xo;
        if (z >= Hz && z < Hz + TZ && xo >= Hx && xo < Hx + TX) {
            int gi = gz * NXd + gx;
            st4(gp + gi, Pv[r]);
            st4(gvx + gi, Vx[r]);
            st4(gvz + gi, Vz[r]);
        }
    }
}

extern "C" void kernel_launch(void* const* d_in, const int* in_sizes, int n_in,
                              void* d_out, int out_size, void* d_ws, size_t ws_size,
                              hipStream_t stream) {
    if (ws_size < WS_NEED_BYTES) return;
    float* ws = (float*)d_ws;
    const void* vp   = d_in[0];
    const void* rho  = d_in[1];
    const void* damp = d_in[2];
    const void* wav  = d_in[3];
    const int* src_x = (const int*)d_in[4];
    const int* src_z = (const int*)d_in[5];
    const int* rcv_x = (const int*)d_in[6];
    const int* rcv_z = (const int*)d_in[7];

    hipMemsetAsync(ws, 0, (size_t)(3 * FSZ) * 4, stream);
    detect_k<<<1, 64, 0, stream>>>((const uint32_t*)vp, (int*)(ws + FLAG_OFF));
    prep_k<<<1024, 256, 0, stream>>>(vp, rho, damp, ws);

    for (int w = 0; w < NTd / KSTEPS; ++w) {
        win_k<<<256, 512, 0, stream>>>(ws, d_out, wav, src_x, src_z,
                                       rcv_x, rcv_z, w * KSTEPS);
    }
}